// Round 18
// baseline (305.191 us; speedup 1.0000x reference)
//
#include <hip/hip_runtime.h>
#include <hip/hip_bf16.h>
#include <math.h>

#define NRES 512
#define CC   128
#define SROW 136   // 272B row stride: 4-row offset = 1088B ≡ 64 mod 128 ->
                   // X1-store kq row-groups split across bank halves (~free).
                   // (128 and 144 both give 8*SROW ≡ 0 mod 128 -> 8-way.)
#define LN_EPS 1e-5f
#define SPLIT_SCALE 1024.0f
#define SPLIT_INV   0.0009765625f

typedef _Float16 half_t;
typedef __attribute__((ext_vector_type(8))) _Float16 f16x8;
typedef __attribute__((ext_vector_type(4))) float f32x4;

__device__ __forceinline__ float sigmoidf_(float x) {
    return 1.0f / (1.0f + __expf(-x));
}

// ---------------------------------------------------------------------------
// Phase A (MFMA, barrier-protected, persistent over 4 i-values):
// R16 VERBATIM except SROW 144->136. Params in LDS (VGPR stays 128 — the
// R12/R17 failures correlate with added register pressure; not risked here).
// ---------------------------------------------------------------------------
__global__ __launch_bounds__(512)
void phaseA_kernel(const float* __restrict__ p, const float* __restrict__ z,
                   const float* __restrict__ mask,
                   const float* __restrict__ Wlp, const float* __restrict__ blp,
                   const float* __restrict__ Wlg, const float* __restrict__ blg,
                   const float* __restrict__ Wrp, const float* __restrict__ brp,
                   const float* __restrict__ Wrg, const float* __restrict__ brg,
                   const float* __restrict__ lnlw, const float* __restrict__ lnlb,
                   const float* __restrict__ lnrw, const float* __restrict__ lnrb,
                   float* __restrict__ SL)
{
    __shared__ __align__(16) half_t sWp_hi[CC*SROW];
    __shared__ __align__(16) half_t sWp_lo[CC*SROW];
    __shared__ __align__(16) half_t sWg  [CC*SROW];
    __shared__ __align__(16) half_t sAX  [128*SROW];
    __shared__ float sbp[CC], sbg[CC], slnw[CC], slnb[CC];
    __shared__ float smask[NRES];
    __shared__ float sred[8][CC];

    const int t    = threadIdx.x;
    const int side = blockIdx.x >> 7;       // 256 blocks: 128 per side
    const int i0   = blockIdx.x & 127;
    const int lane = t & 63;
    const int w    = t >> 6;

    const float* X   = side ? z   : p;
    const float* Wp  = side ? Wrp : Wlp;
    const float* bp  = side ? brp : blp;
    const float* Wg  = side ? Wrg : Wlg;
    const float* bg  = side ? brg : blg;
    const float* lnw = side ? lnrw : lnlw;
    const float* lnb = side ? lnrb : lnlb;
    const bool   use_mask = (side != 0);

    // --- stage weights once per block (amortized over 4 i-values) ---
    {
        const int o = t >> 2, q = t & 3;
        const float* wp_row = Wp + o * CC;
        const float* wg_row = Wg + o * CC;
        #pragma unroll
        for (int b = 0; b < 4; ++b) {
            const int blk  = q * 4 + b;
            const int dblk = blk ^ (o & 7);
            f32x4 lo  = *(const f32x4*)(wp_row + blk*8);
            f32x4 hi  = *(const f32x4*)(wp_row + blk*8 + 4);
            f32x4 lo2 = *(const f32x4*)(wg_row + blk*8);
            f32x4 hi2 = *(const f32x4*)(wg_row + blk*8 + 4);
            f16x8 vh, vl, vg;
            #pragma unroll
            for (int e = 0; e < 4; ++e) {
                float w0 = lo[e], w1 = hi[e];
                half_t h0 = (half_t)w0, h1 = (half_t)w1;
                vh[e] = h0; vh[e+4] = h1;
                vl[e]   = (half_t)((w0 - (float)h0) * SPLIT_SCALE);
                vl[e+4] = (half_t)((w1 - (float)h1) * SPLIT_SCALE);
                vg[e]   = (half_t)lo2[e]; vg[e+4] = (half_t)hi2[e];
            }
            *(f16x8*)&sWp_hi[o*SROW + dblk*8] = vh;
            *(f16x8*)&sWp_lo[o*SROW + dblk*8] = vl;
            *(f16x8*)&sWg  [o*SROW + dblk*8] = vg;
        }
    }
    if (t < CC) { sbp[t] = bp[t]; sbg[t] = bg[t]; slnw[t] = lnw[t]; slnb[t] = lnb[t]; }

    const int r     = t >> 2;
    const int q     = t & 3;
    const int kq    = lane >> 4;
    const int arow  = (w << 4) + (lane & 15);
    const int drow0 = (w << 4) + (kq << 2);

    for (int ii = 0; ii < 4; ++ii) {
        const int i = i0 + (ii << 7);

        if (use_mask) {
            for (int j = t; j < NRES; j += 512) smask[j] = mask[(size_t)i*NRES + j];
        }
        __syncthreads();   // weights (first iter) + smask visible

        float colacc[8];
        #pragma unroll
        for (int c = 0; c < 8; ++c) colacc[c] = 0.f;

        for (int chunk = 0; chunk < 4; ++chunk) {
            const int j0 = chunk * 128;

            // --- LN + hi/lo split; hi -> sAX, lo kept in regs ---
            f16x8 alo_sv[4];
            {
                const float* rowp = X + ((size_t)i*NRES + (j0 + r)) * CC + q*32;
                float vals[32];
                float sum = 0.f, sq = 0.f;
                #pragma unroll
                for (int k = 0; k < 8; ++k) {
                    f32x4 v4 = *(const f32x4*)(rowp + k*4);
                    #pragma unroll
                    for (int e = 0; e < 4; ++e) {
                        float x = v4[e];
                        vals[k*4+e] = x;
                        sum += x; sq += x*x;
                    }
                }
                sum += __shfl_xor(sum, 1); sum += __shfl_xor(sum, 2);
                sq  += __shfl_xor(sq , 1); sq  += __shfl_xor(sq , 2);
                const float m  = sum * (1.f/CC);
                const float rs = rsqrtf(sq * (1.f/CC) - m*m + LN_EPS);
                #pragma unroll
                for (int b = 0; b < 4; ++b) {
                    f16x8 o8;
                    #pragma unroll
                    for (int e = 0; e < 8; ++e) {
                        const int c = q*32 + b*8 + e;
                        float lnv = (vals[b*8+e] - m) * rs * slnw[c] + slnb[c];
                        half_t h = (half_t)lnv;
                        o8[e] = h;
                        alo_sv[b][e] = (half_t)((lnv - (float)h) * SPLIT_SCALE);
                    }
                    *(f16x8*)&sAX[r*SROW + ((q*4+b) ^ (r & 7))*8] = o8;
                }
            }
            __syncthreads();   // A_hi visible

            f16x8 afh[4];
            #pragma unroll
            for (int kk = 0; kk < 4; ++kk)
                afh[kk] = *(const f16x8*)&sAX[arow*SROW + (((kk<<2)+kq) ^ (arow & 7))*8];
            __syncthreads();   // all A_hi reads done

            #pragma unroll
            for (int b = 0; b < 4; ++b)
                *(f16x8*)&sAX[r*SROW + ((q*4+b) ^ (r & 7))*8] = alo_sv[b];
            __syncthreads();   // A_lo visible

            f16x8 afl[4];
            #pragma unroll
            for (int kk = 0; kk < 4; ++kk)
                afl[kk] = *(const f16x8*)&sAX[arow*SROW + (((kk<<2)+kq) ^ (arow & 7))*8];
            __syncthreads();   // all A_lo reads done; sAX free for X1

            // --- pass 1: x1 = A @ Wp^T + bp (split), mask; store fp16 X1 ---
            float xv[8][4];
            float mrow[4];
            if (use_mask) {
                #pragma unroll
                for (int rr = 0; rr < 4; ++rr) mrow[rr] = smask[j0 + drow0 + rr];
            }
            #pragma unroll
            for (int ct = 0; ct < 8; ++ct) {
                const int ocol = (ct << 4) + (lane & 15);
                f32x4 acc1 = {0.f,0.f,0.f,0.f};
                f32x4 acc2 = {0.f,0.f,0.f,0.f};
                #pragma unroll
                for (int kk = 0; kk < 4; ++kk) {
                    const int idx = ocol*SROW + (((kk<<2)+kq) ^ (ocol & 7))*8;
                    f16x8 whi = *(const f16x8*)&sWp_hi[idx];
                    f16x8 wlo = *(const f16x8*)&sWp_lo[idx];
                    acc1 = __builtin_amdgcn_mfma_f32_16x16x32_f16(afh[kk], whi, acc1, 0, 0, 0);
                    acc2 = __builtin_amdgcn_mfma_f32_16x16x32_f16(afh[kk], wlo, acc2, 0, 0, 0);
                    acc2 = __builtin_amdgcn_mfma_f32_16x16x32_f16(afl[kk], whi, acc2, 0, 0, 0);
                }
                const float bias = sbp[ocol];
                #pragma unroll
                for (int rr = 0; rr < 4; ++rr) {
                    float x = acc1[rr] + acc2[rr]*SPLIT_INV + bias;
                    if (use_mask) x *= mrow[rr];
                    xv[ct][rr] = x;
                    const int dr = drow0 + rr;
                    sAX[dr*SROW + (((ocol>>3) ^ (dr & 7))<<3) + (ocol & 7)] = (half_t)x;
                }
            }
            __syncthreads();   // X1 visible

            // --- pass 2: gate + accumulate ---
            f16x8 a2[4];
            #pragma unroll
            for (int kk = 0; kk < 4; ++kk)
                a2[kk] = *(const f16x8*)&sAX[arow*SROW + (((kk<<2)+kq) ^ (arow & 7))*8];
            #pragma unroll
            for (int ct = 0; ct < 8; ++ct) {
                const int ocol = (ct << 4) + (lane & 15);
                f32x4 acc = {0.f,0.f,0.f,0.f};
                #pragma unroll
                for (int kk = 0; kk < 4; ++kk) {
                    f16x8 bfr = *(const f16x8*)&sWg[ocol*SROW + (((kk<<2)+kq) ^ (ocol & 7))*8];
                    acc = __builtin_amdgcn_mfma_f32_16x16x32_f16(a2[kk], bfr, acc, 0, 0, 0);
                }
                const float bias = sbg[ocol];
                float part = 0.f;
                #pragma unroll
                for (int rr = 0; rr < 4; ++rr)
                    part += sigmoidf_(acc[rr] + bias) * xv[ct][rr];
                part += __shfl_xor(part, 16);
                part += __shfl_xor(part, 32);
                colacc[ct] += part;
            }
            __syncthreads();   // pass-2 reads done before next chunk overwrites sAX
        }

        if (lane < 16) {
            #pragma unroll
            for (int ct = 0; ct < 8; ++ct) sred[w][(ct<<4) + lane] = colacc[ct];
        }
        __syncthreads();
        if (t < CC) {
            float s = 0.f;
            #pragma unroll
            for (int ww = 0; ww < 8; ++ww) s += sred[ww][t];
            SL[((size_t)side*NRES + i)*CC + t] = s;
        }
    }
}

// ---------------------------------------------------------------------------
// Phase B (MFMA, persistent over 4 j-chunks, plain-fp16 operands):
//   out[i,j,:] = LN(zl[i] * zr[j]) @ Wz^T + bz   (R16 verbatim, SROW 136)
// ---------------------------------------------------------------------------
__global__ __launch_bounds__(512, 4)
void phaseB_kernel(const float* __restrict__ zl, const float* __restrict__ zr,
                   const float* __restrict__ Wz, const float* __restrict__ bz,
                   const float* __restrict__ lnw, const float* __restrict__ lnb,
                   float* __restrict__ out)
{
    __shared__ __align__(16) half_t sW_hi[CC*SROW];
    __shared__ __align__(16) half_t sAX[128*SROW];
    __shared__ float szl[CC], sbz[CC], slnw[CC], slnb[CC];

    const int t    = threadIdx.x;
    const int i    = blockIdx.x;
    const int lane = t & 63;
    const int w    = t >> 6;

    {
        const int o = t >> 2, q = t & 3;
        const float* wrow = Wz + o * CC;
        #pragma unroll
        for (int b = 0; b < 4; ++b) {
            const int blk  = q*4 + b;
            const int dblk = blk ^ (o & 7);
            f32x4 lo = *(const f32x4*)(wrow + blk*8);
            f32x4 hi = *(const f32x4*)(wrow + blk*8 + 4);
            f16x8 vh;
            #pragma unroll
            for (int e = 0; e < 4; ++e) {
                vh[e] = (half_t)lo[e]; vh[e+4] = (half_t)hi[e];
            }
            *(f16x8*)&sW_hi[o*SROW + dblk*8] = vh;
        }
    }
    if (t < CC) { szl[t] = zl[(size_t)i*CC + t]; sbz[t] = bz[t]; slnw[t] = lnw[t]; slnb[t] = lnb[t]; }
    __syncthreads();

    const int kq    = lane >> 4;
    const int arow  = (w << 4) + (lane & 15);
    const int drow0 = (w << 4) + (kq << 2);

    for (int chunk = 0; chunk < 4; ++chunk) {
        const int j0 = chunk * 128;

        // A = LN(zl[i] * zr[j0+r]) -> sAX (fp16)
        {
            const int r = t >> 2, q = t & 3;
            const float* rowp = zr + (size_t)(j0 + r) * CC + q*32;
            float vals[32];
            float sum = 0.f, sq = 0.f;
            #pragma unroll
            for (int k = 0; k < 8; ++k) {
                f32x4 v4 = *(const f32x4*)(rowp + k*4);
                #pragma unroll
                for (int e = 0; e < 4; ++e) {
                    float x = v4[e] * szl[q*32 + k*4 + e];
                    vals[k*4+e] = x;
                    sum += x; sq += x*x;
                }
            }
            sum += __shfl_xor(sum, 1); sum += __shfl_xor(sum, 2);
            sq  += __shfl_xor(sq , 1); sq  += __shfl_xor(sq , 2);
            const float m  = sum * (1.f/CC);
            const float rs = rsqrtf(sq * (1.f/CC) - m*m + LN_EPS);
            #pragma unroll
            for (int b = 0; b < 4; ++b) {
                f16x8 o8;
                #pragma unroll
                for (int e = 0; e < 8; ++e) {
                    const int c = q*32 + b*8 + e;
                    o8[e] = (half_t)((vals[b*8+e] - m) * rs * slnw[c] + slnb[c]);
                }
                *(f16x8*)&sAX[r*SROW + ((q*4+b) ^ (r & 7))*8] = o8;
            }
        }
        __syncthreads();   // A visible

        f16x8 afh[4];
        #pragma unroll
        for (int kk = 0; kk < 4; ++kk)
            afh[kk] = *(const f16x8*)&sAX[arow*SROW + (((kk<<2)+kq) ^ (arow & 7))*8];

        #pragma unroll
        for (int ct = 0; ct < 8; ++ct) {
            const int ocol = (ct << 4) + (lane & 15);
            f32x4 acc1 = {0.f,0.f,0.f,0.f};
            #pragma unroll
            for (int kk = 0; kk < 4; ++kk) {
                const int idx = ocol*SROW + (((kk<<2)+kq) ^ (ocol & 7))*8;
                f16x8 whi = *(const f16x8*)&sW_hi[idx];
                acc1 = __builtin_amdgcn_mfma_f32_16x16x32_f16(afh[kk], whi, acc1, 0, 0, 0);
            }
            const float bias = sbz[ocol];
            #pragma unroll
            for (int rr = 0; rr < 4; ++rr) {
                const size_t j = (size_t)(j0 + drow0 + rr);
                out[((size_t)i*NRES + j)*CC + ocol] = acc1[rr] + bias;
            }
        }
        __syncthreads();   // A reads done before next chunk overwrites sAX
    }
}

extern "C" void kernel_launch(void* const* d_in, const int* in_sizes, int n_in,
                              void* d_out, int out_size, void* d_ws, size_t ws_size,
                              hipStream_t stream)
{
    (void)in_sizes; (void)n_in; (void)out_size; (void)ws_size;
    const float* z      = (const float*)d_in[0];
    const float* p      = (const float*)d_in[1];
    const float* mask   = (const float*)d_in[2];
    const float* w_lp   = (const float*)d_in[3];
    const float* b_lp   = (const float*)d_in[4];
    const float* w_rp   = (const float*)d_in[5];
    const float* b_rp   = (const float*)d_in[6];
    const float* w_lg   = (const float*)d_in[7];
    const float* b_lg   = (const float*)d_in[8];
    const float* w_rg   = (const float*)d_in[9];
    const float* b_rg   = (const float*)d_in[10];
    const float* w_z    = (const float*)d_in[11];
    const float* b_z    = (const float*)d_in[12];
    const float* ln_l_w = (const float*)d_in[13];
    const float* ln_l_b = (const float*)d_in[14];
    const float* ln_r_w = (const float*)d_in[15];
    const float* ln_r_b = (const float*)d_in[16];
    const float* ln_o_w = (const float*)d_in[17];
    const float* ln_o_b = (const float*)d_in[18];
    float* out = (float*)d_out;

    float* zl = (float*)d_ws;              // [512][128]
    float* zr = zl + NRES*CC;              // [512][128]

    // Phase A: 256 blocks (128 per side), each handles 4 i-values
    phaseA_kernel<<<dim3(256), dim3(512), 0, stream>>>(
        p, z, mask, w_lp, b_lp, w_lg, b_lg, w_rp, b_rp, w_rg, b_rg,
        ln_l_w, ln_l_b, ln_r_w, ln_r_b, zl);

    // Phase B: 512 blocks, each handles one i (4 j-chunks)
    phaseB_kernel<<<dim3(NRES), dim3(512), 0, stream>>>(
        zl, zr, w_z, b_z, ln_o_w, ln_o_b, out);
}

// Round 19
// 241.199 us; speedup vs baseline: 1.2653x; 1.2653x over previous
//
#include <hip/hip_runtime.h>
#include <hip/hip_bf16.h>
#include <math.h>

#define NRES 512
#define CC   128
#define SROW 144   // R16-proven. Row base ≡ 16·row? NO: 144*2=288B ≡ 32 mod 128.
                   // Empirically equal to 128 (18.5M); 136 was 3x WORSE (R18).
#define LN_EPS 1e-5f
#define SPLIT_SCALE 1024.0f
#define SPLIT_INV   0.0009765625f

typedef _Float16 half_t;
typedef __attribute__((ext_vector_type(8))) _Float16 f16x8;
typedef __attribute__((ext_vector_type(4))) float f32x4;

__device__ __forceinline__ float sigmoidf_(float x) {
    return 1.0f / (1.0f + __expf(-x));
}

// ---------------------------------------------------------------------------
// Phase A (MFMA, barrier-protected, persistent over 4 i-values):
// R16 VERBATIM minus the a-residual split: A stored once (fp16), w-split kept.
// 4 barriers/chunk instead of 6; 8 pass-1 MFMAs instead of 12.
// ---------------------------------------------------------------------------
__global__ __launch_bounds__(512)
void phaseA_kernel(const float* __restrict__ p, const float* __restrict__ z,
                   const float* __restrict__ mask,
                   const float* __restrict__ Wlp, const float* __restrict__ blp,
                   const float* __restrict__ Wlg, const float* __restrict__ blg,
                   const float* __restrict__ Wrp, const float* __restrict__ brp,
                   const float* __restrict__ Wrg, const float* __restrict__ brg,
                   const float* __restrict__ lnlw, const float* __restrict__ lnlb,
                   const float* __restrict__ lnrw, const float* __restrict__ lnrb,
                   float* __restrict__ SL)
{
    __shared__ __align__(16) half_t sWp_hi[CC*SROW];
    __shared__ __align__(16) half_t sWp_lo[CC*SROW];
    __shared__ __align__(16) half_t sWg  [CC*SROW];
    __shared__ __align__(16) half_t sAX  [128*SROW];
    __shared__ float sbp[CC], sbg[CC], slnw[CC], slnb[CC];
    __shared__ float smask[NRES];
    __shared__ float sred[8][CC];

    const int t    = threadIdx.x;
    const int side = blockIdx.x >> 7;       // 256 blocks: 128 per side
    const int i0   = blockIdx.x & 127;
    const int lane = t & 63;
    const int w    = t >> 6;

    const float* X   = side ? z   : p;
    const float* Wp  = side ? Wrp : Wlp;
    const float* bp  = side ? brp : blp;
    const float* Wg  = side ? Wrg : Wlg;
    const float* bg  = side ? brg : blg;
    const float* lnw = side ? lnrw : lnlw;
    const float* lnb = side ? lnrb : lnlb;
    const bool   use_mask = (side != 0);

    // --- stage weights once per block (amortized over 4 i-values) ---
    {
        const int o = t >> 2, q = t & 3;
        const float* wp_row = Wp + o * CC;
        const float* wg_row = Wg + o * CC;
        #pragma unroll
        for (int b = 0; b < 4; ++b) {
            const int blk  = q * 4 + b;
            const int dblk = blk ^ (o & 7);
            f32x4 lo  = *(const f32x4*)(wp_row + blk*8);
            f32x4 hi  = *(const f32x4*)(wp_row + blk*8 + 4);
            f32x4 lo2 = *(const f32x4*)(wg_row + blk*8);
            f32x4 hi2 = *(const f32x4*)(wg_row + blk*8 + 4);
            f16x8 vh, vl, vg;
            #pragma unroll
            for (int e = 0; e < 4; ++e) {
                float w0 = lo[e], w1 = hi[e];
                half_t h0 = (half_t)w0, h1 = (half_t)w1;
                vh[e] = h0; vh[e+4] = h1;
                vl[e]   = (half_t)((w0 - (float)h0) * SPLIT_SCALE);
                vl[e+4] = (half_t)((w1 - (float)h1) * SPLIT_SCALE);
                vg[e]   = (half_t)lo2[e]; vg[e+4] = (half_t)hi2[e];
            }
            *(f16x8*)&sWp_hi[o*SROW + dblk*8] = vh;
            *(f16x8*)&sWp_lo[o*SROW + dblk*8] = vl;
            *(f16x8*)&sWg  [o*SROW + dblk*8] = vg;
        }
    }
    if (t < CC) { sbp[t] = bp[t]; sbg[t] = bg[t]; slnw[t] = lnw[t]; slnb[t] = lnb[t]; }

    const int r     = t >> 2;
    const int q     = t & 3;
    const int kq    = lane >> 4;
    const int arow  = (w << 4) + (lane & 15);
    const int drow0 = (w << 4) + (kq << 2);

    for (int ii = 0; ii < 4; ++ii) {
        const int i = i0 + (ii << 7);

        if (use_mask) {
            for (int j = t; j < NRES; j += 512) smask[j] = mask[(size_t)i*NRES + j];
        }
        __syncthreads();   // weights (first iter) + smask visible

        float colacc[8];
        #pragma unroll
        for (int c = 0; c < 8; ++c) colacc[c] = 0.f;

        for (int chunk = 0; chunk < 4; ++chunk) {
            const int j0 = chunk * 128;

            // --- LN -> fp16 A -> sAX (no residual) ---
            {
                const float* rowp = X + ((size_t)i*NRES + (j0 + r)) * CC + q*32;
                float vals[32];
                float sum = 0.f, sq = 0.f;
                #pragma unroll
                for (int k = 0; k < 8; ++k) {
                    f32x4 v4 = *(const f32x4*)(rowp + k*4);
                    #pragma unroll
                    for (int e = 0; e < 4; ++e) {
                        float x = v4[e];
                        vals[k*4+e] = x;
                        sum += x; sq += x*x;
                    }
                }
                sum += __shfl_xor(sum, 1); sum += __shfl_xor(sum, 2);
                sq  += __shfl_xor(sq , 1); sq  += __shfl_xor(sq , 2);
                const float m  = sum * (1.f/CC);
                const float rs = rsqrtf(sq * (1.f/CC) - m*m + LN_EPS);
                #pragma unroll
                for (int b = 0; b < 4; ++b) {
                    f16x8 o8;
                    #pragma unroll
                    for (int e = 0; e < 8; ++e) {
                        const int c = q*32 + b*8 + e;
                        o8[e] = (half_t)((vals[b*8+e] - m) * rs * slnw[c] + slnb[c]);
                    }
                    *(f16x8*)&sAX[r*SROW + ((q*4+b) ^ (r & 7))*8] = o8;
                }
            }
            __syncthreads();   // A visible

            f16x8 afh[4];
            #pragma unroll
            for (int kk = 0; kk < 4; ++kk)
                afh[kk] = *(const f16x8*)&sAX[arow*SROW + (((kk<<2)+kq) ^ (arow & 7))*8];
            __syncthreads();   // all A reads done; sAX free for X1

            // --- pass 1: x1 = A @ (Wp_hi + Wp_lo/1024)^T + bp, mask ---
            float xv[8][4];
            float mrow[4];
            if (use_mask) {
                #pragma unroll
                for (int rr = 0; rr < 4; ++rr) mrow[rr] = smask[j0 + drow0 + rr];
            }
            #pragma unroll
            for (int ct = 0; ct < 8; ++ct) {
                const int ocol = (ct << 4) + (lane & 15);
                f32x4 acc1 = {0.f,0.f,0.f,0.f};
                f32x4 acc2 = {0.f,0.f,0.f,0.f};
                #pragma unroll
                for (int kk = 0; kk < 4; ++kk) {
                    const int idx = ocol*SROW + (((kk<<2)+kq) ^ (ocol & 7))*8;
                    f16x8 whi = *(const f16x8*)&sWp_hi[idx];
                    f16x8 wlo = *(const f16x8*)&sWp_lo[idx];
                    acc1 = __builtin_amdgcn_mfma_f32_16x16x32_f16(afh[kk], whi, acc1, 0, 0, 0);
                    acc2 = __builtin_amdgcn_mfma_f32_16x16x32_f16(afh[kk], wlo, acc2, 0, 0, 0);
                }
                const float bias = sbp[ocol];
                #pragma unroll
                for (int rr = 0; rr < 4; ++rr) {
                    float x = acc1[rr] + acc2[rr]*SPLIT_INV + bias;
                    if (use_mask) x *= mrow[rr];
                    xv[ct][rr] = x;
                    const int dr = drow0 + rr;
                    sAX[dr*SROW + (((ocol>>3) ^ (dr & 7))<<3) + (ocol & 7)] = (half_t)x;
                }
            }
            __syncthreads();   // X1 visible

            // --- pass 2: gate + accumulate ---
            f16x8 a2[4];
            #pragma unroll
            for (int kk = 0; kk < 4; ++kk)
                a2[kk] = *(const f16x8*)&sAX[arow*SROW + (((kk<<2)+kq) ^ (arow & 7))*8];
            #pragma unroll
            for (int ct = 0; ct < 8; ++ct) {
                const int ocol = (ct << 4) + (lane & 15);
                f32x4 acc = {0.f,0.f,0.f,0.f};
                #pragma unroll
                for (int kk = 0; kk < 4; ++kk) {
                    f16x8 bfr = *(const f16x8*)&sWg[ocol*SROW + (((kk<<2)+kq) ^ (ocol & 7))*8];
                    acc = __builtin_amdgcn_mfma_f32_16x16x32_f16(a2[kk], bfr, acc, 0, 0, 0);
                }
                const float bias = sbg[ocol];
                float part = 0.f;
                #pragma unroll
                for (int rr = 0; rr < 4; ++rr)
                    part += sigmoidf_(acc[rr] + bias) * xv[ct][rr];
                part += __shfl_xor(part, 16);
                part += __shfl_xor(part, 32);
                colacc[ct] += part;
            }
            __syncthreads();   // pass-2 reads done before next chunk overwrites sAX
        }

        if (lane < 16) {
            #pragma unroll
            for (int ct = 0; ct < 8; ++ct) sred[w][(ct<<4) + lane] = colacc[ct];
        }
        __syncthreads();
        if (t < CC) {
            float s = 0.f;
            #pragma unroll
            for (int ww = 0; ww < 8; ++ww) s += sred[ww][t];
            SL[((size_t)side*NRES + i)*CC + t] = s;
        }
    }
}

// ---------------------------------------------------------------------------
// Phase B (MFMA, persistent over 4 j-chunks, plain-fp16 operands):
//   out[i,j,:] = LN(zl[i] * zr[j]) @ Wz^T + bz   (R16 verbatim)
// ---------------------------------------------------------------------------
__global__ __launch_bounds__(512, 4)
void phaseB_kernel(const float* __restrict__ zl, const float* __restrict__ zr,
                   const float* __restrict__ Wz, const float* __restrict__ bz,
                   const float* __restrict__ lnw, const float* __restrict__ lnb,
                   float* __restrict__ out)
{
    __shared__ __align__(16) half_t sW_hi[CC*SROW];
    __shared__ __align__(16) half_t sAX[128*SROW];
    __shared__ float szl[CC], sbz[CC], slnw[CC], slnb[CC];

    const int t    = threadIdx.x;
    const int i    = blockIdx.x;
    const int lane = t & 63;
    const int w    = t >> 6;

    {
        const int o = t >> 2, q = t & 3;
        const float* wrow = Wz + o * CC;
        #pragma unroll
        for (int b = 0; b < 4; ++b) {
            const int blk  = q*4 + b;
            const int dblk = blk ^ (o & 7);
            f32x4 lo = *(const f32x4*)(wrow + blk*8);
            f32x4 hi = *(const f32x4*)(wrow + blk*8 + 4);
            f16x8 vh;
            #pragma unroll
            for (int e = 0; e < 4; ++e) {
                vh[e] = (half_t)lo[e]; vh[e+4] = (half_t)hi[e];
            }
            *(f16x8*)&sW_hi[o*SROW + dblk*8] = vh;
        }
    }
    if (t < CC) { szl[t] = zl[(size_t)i*CC + t]; sbz[t] = bz[t]; slnw[t] = lnw[t]; slnb[t] = lnb[t]; }
    __syncthreads();

    const int kq    = lane >> 4;
    const int arow  = (w << 4) + (lane & 15);
    const int drow0 = (w << 4) + (kq << 2);

    for (int chunk = 0; chunk < 4; ++chunk) {
        const int j0 = chunk * 128;

        // A = LN(zl[i] * zr[j0+r]) -> sAX (fp16)
        {
            const int r = t >> 2, q = t & 3;
            const float* rowp = zr + (size_t)(j0 + r) * CC + q*32;
            float vals[32];
            float sum = 0.f, sq = 0.f;
            #pragma unroll
            for (int k = 0; k < 8; ++k) {
                f32x4 v4 = *(const f32x4*)(rowp + k*4);
                #pragma unroll
                for (int e = 0; e < 4; ++e) {
                    float x = v4[e] * szl[q*32 + k*4 + e];
                    vals[k*4+e] = x;
                    sum += x; sq += x*x;
                }
            }
            sum += __shfl_xor(sum, 1); sum += __shfl_xor(sum, 2);
            sq  += __shfl_xor(sq , 1); sq  += __shfl_xor(sq , 2);
            const float m  = sum * (1.f/CC);
            const float rs = rsqrtf(sq * (1.f/CC) - m*m + LN_EPS);
            #pragma unroll
            for (int b = 0; b < 4; ++b) {
                f16x8 o8;
                #pragma unroll
                for (int e = 0; e < 8; ++e) {
                    const int c = q*32 + b*8 + e;
                    o8[e] = (half_t)((vals[b*8+e] - m) * rs * slnw[c] + slnb[c]);
                }
                *(f16x8*)&sAX[r*SROW + ((q*4+b) ^ (r & 7))*8] = o8;
            }
        }
        __syncthreads();   // A visible

        f16x8 afh[4];
        #pragma unroll
        for (int kk = 0; kk < 4; ++kk)
            afh[kk] = *(const f16x8*)&sAX[arow*SROW + (((kk<<2)+kq) ^ (arow & 7))*8];

        #pragma unroll
        for (int ct = 0; ct < 8; ++ct) {
            const int ocol = (ct << 4) + (lane & 15);
            f32x4 acc1 = {0.f,0.f,0.f,0.f};
            #pragma unroll
            for (int kk = 0; kk < 4; ++kk) {
                const int idx = ocol*SROW + (((kk<<2)+kq) ^ (ocol & 7))*8;
                f16x8 whi = *(const f16x8*)&sW_hi[idx];
                acc1 = __builtin_amdgcn_mfma_f32_16x16x32_f16(afh[kk], whi, acc1, 0, 0, 0);
            }
            const float bias = sbz[ocol];
            #pragma unroll
            for (int rr = 0; rr < 4; ++rr) {
                const size_t j = (size_t)(j0 + drow0 + rr);
                out[((size_t)i*NRES + j)*CC + ocol] = acc1[rr] + bias;
            }
        }
        __syncthreads();   // A reads done before next chunk overwrites sAX
    }
}

extern "C" void kernel_launch(void* const* d_in, const int* in_sizes, int n_in,
                              void* d_out, int out_size, void* d_ws, size_t ws_size,
                              hipStream_t stream)
{
    (void)in_sizes; (void)n_in; (void)out_size; (void)ws_size;
    const float* z      = (const float*)d_in[0];
    const float* p      = (const float*)d_in[1];
    const float* mask   = (const float*)d_in[2];
    const float* w_lp   = (const float*)d_in[3];
    const float* b_lp   = (const float*)d_in[4];
    const float* w_rp   = (const float*)d_in[5];
    const float* b_rp   = (const float*)d_in[6];
    const float* w_lg   = (const float*)d_in[7];
    const float* b_lg   = (const float*)d_in[8];
    const float* w_rg   = (const float*)d_in[9];
    const float* b_rg   = (const float*)d_in[10];
    const float* w_z    = (const float*)d_in[11];
    const float* b_z    = (const float*)d_in[12];
    const float* ln_l_w = (const float*)d_in[13];
    const float* ln_l_b = (const float*)d_in[14];
    const float* ln_r_w = (const float*)d_in[15];
    const float* ln_r_b = (const float*)d_in[16];
    const float* ln_o_w = (const float*)d_in[17];
    const float* ln_o_b = (const float*)d_in[18];
    float* out = (float*)d_out;

    float* zl = (float*)d_ws;              // [512][128]
    float* zr = zl + NRES*CC;              // [512][128]

    // Phase A: 256 blocks (128 per side), each handles 4 i-values
    phaseA_kernel<<<dim3(256), dim3(512), 0, stream>>>(
        p, z, mask, w_lp, b_lp, w_lg, b_lg, w_rp, b_rp, w_rg, b_rg,
        ln_l_w, ln_l_b, ln_r_w, ln_r_b, zl);

    // Phase B: 512 blocks, each handles one i (4 j-chunks)
    phaseB_kernel<<<dim3(NRES), dim3(512), 0, stream>>>(
        zl, zr, w_z, b_z, ln_o_w, ln_o_b, out);
}